// Round 1
// baseline (3029.262 us; speedup 1.0000x reference)
//
#include <hip/hip_runtime.h>

// GCN 2-layer forward on MI355X.
// x:[N,128] f32, edge_index:[2,E] int32, W1:[128,64], b1:[64], W2:[64,64], b2:[64]
// out:[N,64] f32

__global__ __launch_bounds__(256) void k_deg(const int* __restrict__ dst,
                                             float* __restrict__ deg, int E) {
  int i = blockIdx.x * 256 + threadIdx.x;
  if (i < E) atomicAdd(&deg[dst[i]], 1.0f);
}

__global__ __launch_bounds__(256) void k_dinv(const float* __restrict__ deg,
                                              float* __restrict__ dinv, int N) {
  int i = blockIdx.x * 256 + threadIdx.x;
  if (i < N) dinv[i] = rsqrtf(deg[i] + 1.0f);  // self-loop adds 1
}

// H[node, j] = sum_k X[node, k] * W[k, j]   (W row-major [K,64])
// One thread per node; W reads are wave-uniform -> scalar loads (s_load),
// keeping the VALU pipe for the 8192/4096 FMAs per thread.
template <int K>
__global__ __launch_bounds__(256) void k_gemm(const float* __restrict__ X,
                                              const float* __restrict__ W,
                                              float* __restrict__ H, int N) {
  int node = blockIdx.x * 256 + threadIdx.x;
  if (node >= N) return;
  const float* xr = X + (size_t)node * K;
  float acc[64];
#pragma unroll
  for (int j = 0; j < 64; ++j) acc[j] = 0.f;
  for (int k0 = 0; k0 < K; k0 += 4) {
    float4 xv = *reinterpret_cast<const float4*>(xr + k0);
#pragma unroll
    for (int j = 0; j < 64; ++j) {
      acc[j] = fmaf(xv.x, W[(k0 + 0) * 64 + j], acc[j]);
      acc[j] = fmaf(xv.y, W[(k0 + 1) * 64 + j], acc[j]);
      acc[j] = fmaf(xv.z, W[(k0 + 2) * 64 + j], acc[j]);
      acc[j] = fmaf(xv.w, W[(k0 + 3) * 64 + j], acc[j]);
    }
  }
  float* hr = H + (size_t)node * 64;
#pragma unroll
  for (int j = 0; j < 64; j += 4) {
    float4 o;
    o.x = acc[j]; o.y = acc[j + 1]; o.z = acc[j + 2]; o.w = acc[j + 3];
    *reinterpret_cast<float4*>(hr + j) = o;
  }
}

// msg = h[src] * dinv[src]*dinv[dst]; agg[dst] += msg
// 16 threads per edge, float4 gather + 4 fire-and-forget f32 atomics each.
__global__ __launch_bounds__(256) void k_scatter(const int* __restrict__ src,
                                                 const int* __restrict__ dst,
                                                 const float* __restrict__ h,
                                                 const float* __restrict__ dinv,
                                                 float* __restrict__ agg, int E) {
  int t = blockIdx.x * 256 + threadIdx.x;
  int e = t >> 4;
  if (e >= E) return;
  int q = (t & 15) * 4;
  int s = src[e], d = dst[e];
  float norm = dinv[s] * dinv[d];
  float4 m = *reinterpret_cast<const float4*>(h + (size_t)s * 64 + q);
  float* o = agg + (size_t)d * 64 + q;
  atomicAdd(o + 0, m.x * norm);
  atomicAdd(o + 1, m.y * norm);
  atomicAdd(o + 2, m.z * norm);
  atomicAdd(o + 3, m.w * norm);
}

// out = agg + h * dinv^2 + bias  (+ optional relu). Elementwise, in-place safe.
__global__ __launch_bounds__(256) void k_combine(const float* __restrict__ agg,
                                                 const float* __restrict__ h,
                                                 const float* __restrict__ dinv,
                                                 const float* __restrict__ bias,
                                                 float* __restrict__ out, int N,
                                                 int relu) {
  int i = blockIdx.x * 256 + threadIdx.x;
  if (i >= N * 64) return;
  int node = i >> 6, j = i & 63;
  float di = dinv[node];
  float v = agg[i] + h[i] * di * di + bias[j];
  if (relu) v = fmaxf(v, 0.f);
  out[i] = v;
}

extern "C" void kernel_launch(void* const* d_in, const int* in_sizes, int n_in,
                              void* d_out, int out_size, void* d_ws, size_t ws_size,
                              hipStream_t stream) {
  const float* x  = (const float*)d_in[0];
  const int*   ei = (const int*)d_in[1];
  const float* W1 = (const float*)d_in[2];
  const float* b1 = (const float*)d_in[3];
  const float* W2 = (const float*)d_in[4];
  const float* b2 = (const float*)d_in[5];
  float* out = (float*)d_out;

  const int N = in_sizes[0] / 128;  // 100000
  const int E = in_sizes[1] / 2;    // 1600000
  const int* src = ei;
  const int* dstv = ei + E;

  float* ws   = (float*)d_ws;
  float* deg  = ws;                       // N floats
  float* dinv = ws + 102400;              // N floats
  float* bufA = ws + 204800;              // N*64 floats (h1 -> h2)
  float* bufB = bufA + 6401024;           // N*64 floats (agg1/out1 -> agg2)
  const size_t n64 = (size_t)N * 64;

  // degree + dinv (shared by both convs)
  hipMemsetAsync(deg, 0, (size_t)N * 4, stream);
  k_deg<<<(E + 255) / 256, 256, 0, stream>>>(dstv, deg, E);
  k_dinv<<<(N + 255) / 256, 256, 0, stream>>>(deg, dinv, N);

  // ---- conv1 ----
  k_gemm<128><<<(N + 255) / 256, 256, 0, stream>>>(x, W1, bufA, N);
  hipMemsetAsync(bufB, 0, n64 * 4, stream);
  k_scatter<<<(E * 16 + 255) / 256, 256, 0, stream>>>(src, dstv, bufA, dinv, bufB, E);
  k_combine<<<((int)n64 + 255) / 256, 256, 0, stream>>>(bufB, bufA, dinv, b1, bufB, N, 1);

  // ---- conv2 ----
  k_gemm<64><<<(N + 255) / 256, 256, 0, stream>>>(bufB, W2, bufA, N);
  hipMemsetAsync(bufB, 0, n64 * 4, stream);
  k_scatter<<<(E * 16 + 255) / 256, 256, 0, stream>>>(src, dstv, bufA, dinv, bufB, E);
  k_combine<<<((int)n64 + 255) / 256, 256, 0, stream>>>(bufB, bufA, dinv, b2, out, N, 0);
}

// Round 2
// 569.168 us; speedup vs baseline: 5.3223x; 5.3223x over previous
//
#include <hip/hip_runtime.h>

// GCN 2-layer forward, atomic-free aggregation via on-device CSR.
// x:[N,128] f32, edge_index:[2,E] int32, W1:[128,64], b1:[64], W2:[64,64], b2:[64]

__global__ __launch_bounds__(256) void k_count(const int* __restrict__ dst,
                                               int* __restrict__ cnt, int E) {
  int i = blockIdx.x * 256 + threadIdx.x;
  if (i < E) atomicAdd(&cnt[dst[i]], 1);
}

__global__ __launch_bounds__(256) void k_dinv(const int* __restrict__ cnt,
                                              float* __restrict__ dinv, int N) {
  int i = blockIdx.x * 256 + threadIdx.x;
  if (i < N) dinv[i] = rsqrtf((float)cnt[i] + 1.0f);  // self-loop adds 1
}

// ---- 3-kernel exclusive scan of cnt[N] -> row[N], block sums in bsum ----
__global__ __launch_bounds__(256) void k_scan1(const int* __restrict__ cnt,
                                               int* __restrict__ row,
                                               int* __restrict__ bsum, int N) {
  __shared__ int tmp[256];
  int i = blockIdx.x * 256 + threadIdx.x;
  int v = (i < N) ? cnt[i] : 0;
  tmp[threadIdx.x] = v;
  __syncthreads();
  for (int off = 1; off < 256; off <<= 1) {
    int t = (threadIdx.x >= off) ? tmp[threadIdx.x - off] : 0;
    __syncthreads();
    tmp[threadIdx.x] += t;
    __syncthreads();
  }
  if (i < N) row[i] = tmp[threadIdx.x] - v;  // exclusive
  if (threadIdx.x == 255) bsum[blockIdx.x] = tmp[255];
}

__global__ __launch_bounds__(512) void k_scan2(int* __restrict__ bsum, int nb) {
  __shared__ int tmp[512];
  int v = (threadIdx.x < nb) ? bsum[threadIdx.x] : 0;
  tmp[threadIdx.x] = v;
  __syncthreads();
  for (int off = 1; off < 512; off <<= 1) {
    int t = (threadIdx.x >= off) ? tmp[threadIdx.x - off] : 0;
    __syncthreads();
    tmp[threadIdx.x] += t;
    __syncthreads();
  }
  if (threadIdx.x < nb) bsum[threadIdx.x] = tmp[threadIdx.x] - v;  // exclusive
}

__global__ __launch_bounds__(256) void k_scan3(int* __restrict__ row,
                                               const int* __restrict__ bsum,
                                               int N, int E) {
  int i = blockIdx.x * 256 + threadIdx.x;
  if (i < N) row[i] += bsum[blockIdx.x];
  if (i == 0) row[N] = E;
}

// Bin incoming edges by dst: eidx[row[d] + k] = src of k-th in-edge of d.
__global__ __launch_bounds__(256) void k_fill(const int* __restrict__ src,
                                              const int* __restrict__ dst,
                                              const int* __restrict__ row,
                                              int* __restrict__ fillc,
                                              int* __restrict__ eidx, int E) {
  int e = blockIdx.x * 256 + threadIdx.x;
  if (e < E) {
    int d = dst[e];
    int p = row[d] + atomicAdd(&fillc[d], 1);
    eidx[p] = src[e];
  }
}

// HS[node, j] = dinv[node] * sum_k X[node, k] * W[k, j]   (pre-scaled rows)
template <int K>
__global__ __launch_bounds__(256) void k_gemm(const float* __restrict__ X,
                                              const float* __restrict__ W,
                                              const float* __restrict__ dinv,
                                              float* __restrict__ HS, int N) {
  int node = blockIdx.x * 256 + threadIdx.x;
  if (node >= N) return;
  const float* xr = X + (size_t)node * K;
  float acc[64];
#pragma unroll
  for (int j = 0; j < 64; ++j) acc[j] = 0.f;
  for (int k0 = 0; k0 < K; k0 += 4) {
    float4 xv = *reinterpret_cast<const float4*>(xr + k0);
#pragma unroll
    for (int j = 0; j < 64; ++j) {
      acc[j] = fmaf(xv.x, W[(k0 + 0) * 64 + j], acc[j]);
      acc[j] = fmaf(xv.y, W[(k0 + 1) * 64 + j], acc[j]);
      acc[j] = fmaf(xv.z, W[(k0 + 2) * 64 + j], acc[j]);
      acc[j] = fmaf(xv.w, W[(k0 + 3) * 64 + j], acc[j]);
    }
  }
  float di = dinv[node];
  float* hr = HS + (size_t)node * 64;
#pragma unroll
  for (int j = 0; j < 64; j += 4) {
    float4 o;
    o.x = acc[j] * di; o.y = acc[j + 1] * di;
    o.z = acc[j + 2] * di; o.w = acc[j + 3] * di;
    *reinterpret_cast<float4*>(hr + j) = o;
  }
}

// One wave per node, lane = feature. hs rows are pre-scaled by dinv[src], so:
// out[d] = dinv[d]*(sum_{s in in(d)} hs[s] + hs[d]) + bias   (+relu)
__global__ __launch_bounds__(256) void k_agg(const float* __restrict__ hs,
                                             const int* __restrict__ row,
                                             const int* __restrict__ eidx,
                                             const float* __restrict__ dinv,
                                             const float* __restrict__ bias,
                                             float* __restrict__ out, int N,
                                             int relu) {
  int gid = blockIdx.x * 256 + threadIdx.x;
  int node = gid >> 6, lane = gid & 63;
  if (node >= N) return;
  int beg = row[node], end = row[node + 1];
  float acc0 = 0.f, acc1 = 0.f;
  int e = beg;
  for (; e + 1 < end; e += 2) {
    int s0 = eidx[e], s1 = eidx[e + 1];
    acc0 += hs[(size_t)s0 * 64 + lane];
    acc1 += hs[(size_t)s1 * 64 + lane];
  }
  if (e < end) acc0 += hs[(size_t)eidx[e] * 64 + lane];
  float dd = dinv[node];
  float v = dd * (acc0 + acc1 + hs[(size_t)node * 64 + lane]) + bias[lane];
  if (relu) v = fmaxf(v, 0.f);
  out[(size_t)node * 64 + lane] = v;
}

extern "C" void kernel_launch(void* const* d_in, const int* in_sizes, int n_in,
                              void* d_out, int out_size, void* d_ws, size_t ws_size,
                              hipStream_t stream) {
  const float* x  = (const float*)d_in[0];
  const int*   ei = (const int*)d_in[1];
  const float* W1 = (const float*)d_in[2];
  const float* b1 = (const float*)d_in[3];
  const float* W2 = (const float*)d_in[4];
  const float* b2 = (const float*)d_in[5];
  float* out = (float*)d_out;

  const int N = in_sizes[0] / 128;  // 100000
  const int E = in_sizes[1] / 2;    // 1600000
  const int* src = ei;
  const int* dstv = ei + E;

  // workspace layout (4B units), ~33.6 MB total
  int*   cnt   = (int*)d_ws;                 // [N]
  int*   row   = cnt + 102400;               // [N+1]
  int*   fillc = cnt + 204800;               // [N]
  float* dinv  = (float*)(cnt + 307200);     // [N]
  int*   bsum  = cnt + 409600;               // [512]
  int*   eidx  = cnt + 410112;               // [E]
  float* bufA  = (float*)(cnt + 2010112);    // [N*64], 16B-aligned

  const int nb = (N + 255) / 256;

  // ---- CSR build (shared by both convs) ----
  hipMemsetAsync(cnt, 0, (size_t)N * 4, stream);
  hipMemsetAsync(fillc, 0, (size_t)N * 4, stream);
  k_count<<<(E + 255) / 256, 256, 0, stream>>>(dstv, cnt, E);
  k_dinv<<<nb, 256, 0, stream>>>(cnt, dinv, N);
  k_scan1<<<nb, 256, 0, stream>>>(cnt, row, bsum, N);
  k_scan2<<<1, 512, 0, stream>>>(bsum, nb);
  k_scan3<<<nb, 256, 0, stream>>>(row, bsum, N, E);
  k_fill<<<(E + 255) / 256, 256, 0, stream>>>(src, dstv, row, fillc, eidx, E);

  // ---- conv1: hs1 = dinv*(x@W1) -> agg -> relu -> d_out ----
  k_gemm<128><<<nb, 256, 0, stream>>>(x, W1, dinv, bufA, N);
  k_agg<<<(N * 64 + 255) / 256, 256, 0, stream>>>(bufA, row, eidx, dinv, b1, out, N, 1);

  // ---- conv2: hs2 = dinv*(out@W2) -> agg -> d_out ----
  k_gemm<64><<<nb, 256, 0, stream>>>(out, W2, dinv, bufA, N);
  k_agg<<<(N * 64 + 255) / 256, 256, 0, stream>>>(bufA, row, eidx, dinv, b2, out, N, 0);
}

// Round 4
// 504.647 us; speedup vs baseline: 6.0027x; 1.1279x over previous
//
#include <hip/hip_runtime.h>

// GCN 2-layer forward, atomic-free aggregation via on-device CSR.
// x:[N,128] f32, edge_index:[2,E] int32, W1:[128,64], b1:[64], W2:[64,64], b2:[64]

__global__ __launch_bounds__(256) void k_count(const int* __restrict__ dst,
                                               int* __restrict__ cnt, int E) {
  int i = blockIdx.x * 256 + threadIdx.x;
  if (i < E) atomicAdd(&cnt[dst[i]], 1);
}

__global__ __launch_bounds__(256) void k_dinv(const int* __restrict__ cnt,
                                              float* __restrict__ dinv, int N) {
  int i = blockIdx.x * 256 + threadIdx.x;
  if (i < N) dinv[i] = rsqrtf((float)cnt[i] + 1.0f);  // self-loop adds 1
}

// ---- 3-kernel exclusive scan of cnt[N] -> row[N], block sums in bsum ----
__global__ __launch_bounds__(256) void k_scan1(const int* __restrict__ cnt,
                                               int* __restrict__ row,
                                               int* __restrict__ bsum, int N) {
  __shared__ int tmp[256];
  int i = blockIdx.x * 256 + threadIdx.x;
  int v = (i < N) ? cnt[i] : 0;
  tmp[threadIdx.x] = v;
  __syncthreads();
  for (int off = 1; off < 256; off <<= 1) {
    int t = (threadIdx.x >= off) ? tmp[threadIdx.x - off] : 0;
    __syncthreads();
    tmp[threadIdx.x] += t;
    __syncthreads();
  }
  if (i < N) row[i] = tmp[threadIdx.x] - v;  // exclusive
  if (threadIdx.x == 255) bsum[blockIdx.x] = tmp[255];
}

__global__ __launch_bounds__(512) void k_scan2(int* __restrict__ bsum, int nb) {
  __shared__ int tmp[512];
  int v = (threadIdx.x < nb) ? bsum[threadIdx.x] : 0;
  tmp[threadIdx.x] = v;
  __syncthreads();
  for (int off = 1; off < 512; off <<= 1) {
    int t = (threadIdx.x >= off) ? tmp[threadIdx.x - off] : 0;
    __syncthreads();
    tmp[threadIdx.x] += t;
    __syncthreads();
  }
  if (threadIdx.x < nb) bsum[threadIdx.x] = tmp[threadIdx.x] - v;  // exclusive
}

__global__ __launch_bounds__(256) void k_scan3(int* __restrict__ row,
                                               const int* __restrict__ bsum,
                                               int N, int E) {
  int i = blockIdx.x * 256 + threadIdx.x;
  if (i < N) row[i] += bsum[blockIdx.x];
  if (i == 0) row[N] = E;
}

// Bin incoming edges by dst, XCD-partitioned: block b owns dst class b&7
// (class = (d>>11)&7). All writers of a given eidx/fillc line sit on one XCD
// (blockIdx%8 -> XCD), so lines are written back once instead of 16x.
#define FILL_CS 8192
__global__ __launch_bounds__(256) void k_fill(const int* __restrict__ src,
                                              const int* __restrict__ dst,
                                              const int* __restrict__ row,
                                              int* __restrict__ fillc,
                                              int* __restrict__ eidx, int E) {
  int r = blockIdx.x & 7;
  int base = (blockIdx.x >> 3) * FILL_CS;
  int end = base + FILL_CS;
  if (end > E) end = E;
  for (int e = base + threadIdx.x; e < end; e += 256) {
    int d = dst[e];
    if (((d >> 11) & 7) == r) {
      int p = row[d] + atomicAdd(&fillc[d], 1);
      eidx[p] = src[e];
    }
  }
}

// HS[node, j] = dinv[node] * sum_k X[node, k] * W[k, j]   (pre-scaled rows)
template <int K>
__global__ __launch_bounds__(256) void k_gemm(const float* __restrict__ X,
                                              const float* __restrict__ W,
                                              const float* __restrict__ dinv,
                                              float* __restrict__ HS, int N) {
  int node = blockIdx.x * 256 + threadIdx.x;
  if (node >= N) return;
  const float* xr = X + (size_t)node * K;
  float acc[64];
#pragma unroll
  for (int j = 0; j < 64; ++j) acc[j] = 0.f;
  for (int k0 = 0; k0 < K; k0 += 4) {
    float4 xv = *reinterpret_cast<const float4*>(xr + k0);
#pragma unroll
    for (int j = 0; j < 64; ++j) {
      acc[j] = fmaf(xv.x, W[(k0 + 0) * 64 + j], acc[j]);
      acc[j] = fmaf(xv.y, W[(k0 + 1) * 64 + j], acc[j]);
      acc[j] = fmaf(xv.z, W[(k0 + 2) * 64 + j], acc[j]);
      acc[j] = fmaf(xv.w, W[(k0 + 3) * 64 + j], acc[j]);
    }
  }
  float di = dinv[node];
  float* hr = HS + (size_t)node * 64;
#pragma unroll
  for (int j = 0; j < 64; j += 4) {
    float4 o;
    o.x = acc[j] * di; o.y = acc[j + 1] * di;
    o.z = acc[j + 2] * di; o.w = acc[j + 3] * di;
    *reinterpret_cast<float4*>(hr + j) = o;
  }
}

// One wave per node, lane = feature. hs rows are pre-scaled by dinv[src]:
// out[d] = dinv[d]*(sum_{s in in(d)} hs[s] + hs[d]) + bias   (+relu)
__global__ __launch_bounds__(256) void k_agg(const float* __restrict__ hs,
                                             const int* __restrict__ row,
                                             const int* __restrict__ eidx,
                                             const float* __restrict__ dinv,
                                             const float* __restrict__ bias,
                                             float* __restrict__ out, int N,
                                             int relu) {
  int gid = blockIdx.x * 256 + threadIdx.x;
  int node = gid >> 6, lane = gid & 63;
  if (node >= N) return;
  int beg = row[node], end = row[node + 1];
  float a0 = 0.f, a1 = 0.f, a2 = 0.f, a3 = 0.f;
  int e = beg;
  for (; e + 3 < end; e += 4) {
    int s0 = eidx[e], s1 = eidx[e + 1], s2 = eidx[e + 2], s3 = eidx[e + 3];
    a0 += hs[(size_t)s0 * 64 + lane];
    a1 += hs[(size_t)s1 * 64 + lane];
    a2 += hs[(size_t)s2 * 64 + lane];
    a3 += hs[(size_t)s3 * 64 + lane];
  }
  for (; e < end; ++e) a0 += hs[(size_t)eidx[e] * 64 + lane];
  float dd = dinv[node];
  float v = dd * ((a0 + a1) + (a2 + a3) + hs[(size_t)node * 64 + lane]) + bias[lane];
  if (relu) v = fmaxf(v, 0.f);
  out[(size_t)node * 64 + lane] = v;
}

extern "C" void kernel_launch(void* const* d_in, const int* in_sizes, int n_in,
                              void* d_out, int out_size, void* d_ws, size_t ws_size,
                              hipStream_t stream) {
  const float* x  = (const float*)d_in[0];
  const int*   ei = (const int*)d_in[1];
  const float* W1 = (const float*)d_in[2];
  const float* b1 = (const float*)d_in[3];
  const float* W2 = (const float*)d_in[4];
  const float* b2 = (const float*)d_in[5];
  float* out = (float*)d_out;

  const int N = in_sizes[0] / 128;  // 100000
  const int E = in_sizes[1] / 2;    // 1600000
  const int* src = ei;
  const int* dstv = ei + E;

  // workspace layout (4B units), ~33.6 MB total
  int*   cnt   = (int*)d_ws;                 // [N]
  int*   row   = cnt + 102400;               // [N+1]
  int*   fillc = cnt + 204800;               // [N]
  float* dinv  = (float*)(cnt + 307200);     // [N]
  int*   bsum  = cnt + 409600;               // [512]
  int*   eidx  = cnt + 410112;               // [E]
  float* bufA  = (float*)(cnt + 2010112);    // [N*64], 16B-aligned

  const int nb = (N + 255) / 256;

  // ---- CSR build (shared by both convs) ----
  hipMemsetAsync(cnt, 0, (size_t)N * 4, stream);
  hipMemsetAsync(fillc, 0, (size_t)N * 4, stream);
  k_count<<<(E + 255) / 256, 256, 0, stream>>>(dstv, cnt, E);
  k_dinv<<<nb, 256, 0, stream>>>(cnt, dinv, N);
  k_scan1<<<nb, 256, 0, stream>>>(cnt, row, bsum, N);
  k_scan2<<<1, 512, 0, stream>>>(bsum, nb);
  k_scan3<<<nb, 256, 0, stream>>>(row, bsum, N, E);
  {
    int nchunk = (E + FILL_CS - 1) / FILL_CS;
    k_fill<<<nchunk * 8, 256, 0, stream>>>(src, dstv, row, fillc, eidx, E);
  }

  // ---- conv1: hs1 = dinv*(x@W1) -> agg -> relu -> d_out ----
  k_gemm<128><<<nb, 256, 0, stream>>>(x, W1, dinv, bufA, N);
  k_agg<<<(N * 64 + 255) / 256, 256, 0, stream>>>(bufA, row, eidx, dinv, b1, out, N, 1);

  // ---- conv2: hs2 = dinv*(out@W2) -> agg -> d_out ----
  k_gemm<64><<<nb, 256, 0, stream>>>(out, W2, dinv, bufA, N);
  k_agg<<<(N * 64 + 255) / 256, 256, 0, stream>>>(bufA, row, eidx, dinv, b2, out, N, 0);
}